// Round 25
// baseline (388.764 us; speedup 1.0000x reference)
//
#include <hip/hip_runtime.h>
#include <math.h>

#define H 300
#define NLEAF 4096

typedef unsigned int  uint;
typedef unsigned short ushort;
typedef __attribute__((ext_vector_type(8))) short  short8;
typedef __attribute__((ext_vector_type(4))) float  f32x4;

__device__ __forceinline__ float sigmoidf_(float x) { return 1.0f / (1.0f + expf(-x)); }

__device__ __forceinline__ ushort f2bf(float f)
{
    uint u = __float_as_uint(f);
    u += 0x7FFF + ((u >> 16) & 1);
    return (ushort)(u >> 16);
}
__device__ __forceinline__ uint2 pack4(float4 v)
{
    uint2 w;
    w.x = (uint)f2bf(v.x) | ((uint)f2bf(v.y) << 16);
    w.y = (uint)f2bf(v.z) | ((uint)f2bf(v.w) << 16);
    return w;
}

// ---- per-wave MFMA GEMM over FRAGMENT-TILED B, depth-4 prefetch ----
// B tiled as [colTile][kstep][512 ushorts]: fragment (tile,s) contiguous 1024B;
// lane l reads short8 at frag + l*8 — fully coalesced (16B/lane).
// A in LDS (row stride AS): row=lane%16, k=(s0+s)*32+(lane>>4)*8+i.
// C/D col=lane&15, row=(lane>>4)*4+reg (m89-verified).
// Depth-4 rotation fully unrolled (all slot indices compile-time, rule #20).
template<int NT, int KSTEPS, int KT, int AS>
__device__ __forceinline__ void mfma_gemm(const ushort* A_lds, const ushort* __restrict__ Bt,
                                          int tile0, int s0, int lane, f32x4* acc)
{
    const ushort* Ap = A_lds + (lane & 15) * AS + ((lane >> 4) * 8) + s0 * 32;
    const ushort* Bp[NT];
    #pragma unroll
    for (int t = 0; t < NT; ++t)
        Bp[t] = Bt + ((long)(tile0 + t) * KT + s0) * 512 + lane * 8;

    constexpr int D = (KSTEPS < 4) ? KSTEPS : 4;
    short8 aP[D];
    short8 bP[D][NT];
    #pragma unroll
    for (int i = 0; i < D; ++i) {
        aP[i] = *(const short8*)(Ap + i * 32);
        #pragma unroll
        for (int t = 0; t < NT; ++t) bP[i][t] = *(const short8*)(Bp[t] + i * 512);
    }
    #pragma unroll
    for (int s = 0; s < KSTEPS; ++s) {
        const int slot = s % D;
        #pragma unroll
        for (int t = 0; t < NT; ++t)
            acc[t] = __builtin_amdgcn_mfma_f32_16x16x32_bf16(aP[slot], bP[slot][t], acc[t], 0, 0, 0);
        if (s + D < KSTEPS) {
            aP[slot] = *(const short8*)(Ap + (s + D) * 32);
            #pragma unroll
            for (int t = 0; t < NT; ++t)
                bP[slot][t] = *(const short8*)(Bp[t] + (s + D) * 512);
        }
    }
}

// ---- merged prep: tiled-bf16 weights (blocks 0-639) + tags (640-699) ----
// WArzT: 40 tiles x 19 ksteps x 512 (cols 0-299 r, 320-619 z)
// WuTpT: 20 tiles x 19 ksteps x 512 (u)
// WLzuT: 40 tiles x 10 ksteps x 512 (cols 0-299 leaf-z, 320-619 leaf-u)
__global__ __launch_bounds__(256) void prep_k(
    const float* __restrict__ Wr, const float* __restrict__ Wz,
    const float* __restrict__ Wu, const float* __restrict__ tag_table,
    const float* __restrict__ br, const float* __restrict__ bz,
    ushort* __restrict__ WArzT, ushort* __restrict__ WuTpT, ushort* __restrict__ WLzuT,
    float* __restrict__ tag_r, float* __restrict__ tag_z)
{
    __shared__ float te[50];
    int b = blockIdx.x;
    int tid = threadIdx.x;
    if (b < 640) {
        int c = b;
        int tile = c >> 4, cl = c & 15;
        int gate = (c >= 320);
        int cc = gate ? c - 320 : c;
        const float* WA = gate ? Wz : Wr;
        for (int o = tid; o < 76; o += 256) {
            int k0 = o * 8;
            ushort tmp[8];
            #pragma unroll
            for (int i = 0; i < 8; ++i) {
                int k = k0 + i;
                float v = 0.f;
                if (cc < 300) {
                    if (k < 300) v = WA[(350 + k) * H + cc];
                    else if (k >= 304 && k < 604) v = WA[(k + 346) * H + cc];
                }
                tmp[i] = f2bf(v);
            }
            int s = k0 >> 5, kk0 = k0 & 31;
            long pos = ((long)(tile * 19 + s)) * 512 + ((kk0 >> 3) * 16 + cl) * 8;
            uint4 w;
            w.x = (uint)tmp[0] | ((uint)tmp[1] << 16);
            w.y = (uint)tmp[2] | ((uint)tmp[3] << 16);
            w.z = (uint)tmp[4] | ((uint)tmp[5] << 16);
            w.w = (uint)tmp[6] | ((uint)tmp[7] << 16);
            *(uint4*)&WArzT[pos] = w;
        }
        const float* WL = gate ? Wu : Wz;
        for (int o = tid; o < 40; o += 256) {
            int k0 = o * 8;
            ushort tmp[8];
            #pragma unroll
            for (int i = 0; i < 8; ++i) {
                int k = k0 + i;
                float v = (cc < 300 && k < 300) ? WL[k * H + cc] : 0.f;
                tmp[i] = f2bf(v);
            }
            int s = k0 >> 5, kk0 = k0 & 31;
            long pos = ((long)(tile * 10 + s)) * 512 + ((kk0 >> 3) * 16 + cl) * 8;
            uint4 w;
            w.x = (uint)tmp[0] | ((uint)tmp[1] << 16);
            w.y = (uint)tmp[2] | ((uint)tmp[3] << 16);
            w.z = (uint)tmp[4] | ((uint)tmp[5] << 16);
            w.w = (uint)tmp[6] | ((uint)tmp[7] << 16);
            *(uint4*)&WLzuT[pos] = w;
        }
        if (c < 320) {
            for (int o = tid; o < 76; o += 256) {
                int k0 = o * 8;
                ushort tmp[8];
                #pragma unroll
                for (int i = 0; i < 8; ++i) {
                    int k = k0 + i;
                    float v = 0.f;
                    if (c < 300) {
                        if (k < 300) v = Wu[(300 + k) * H + c];
                        else if (k >= 304 && k < 604) v = Wu[(k + 296) * H + c];
                    }
                    tmp[i] = f2bf(v);
                }
                int s = k0 >> 5, kk0 = k0 & 31;
                long pos = ((long)(tile * 19 + s)) * 512 + ((kk0 >> 3) * 16 + cl) * 8;
                uint4 w;
                w.x = (uint)tmp[0] | ((uint)tmp[1] << 16);
                w.y = (uint)tmp[2] | ((uint)tmp[3] << 16);
                w.z = (uint)tmp[4] | ((uint)tmp[5] << 16);
                w.w = (uint)tmp[6] | ((uint)tmp[7] << 16);
                *(uint4*)&WuTpT[pos] = w;
            }
        }
    } else {
        int t = b - 640;                 // 0..59
        if (tid < 50) te[tid] = tag_table[t * 50 + tid];
        __syncthreads();
        for (int k = tid; k < H; k += 256) {
            float ar = br[k], az = bz[k];
            #pragma unroll 10
            for (int j = 0; j < 50; ++j) {
                float tv = te[j];
                ar = fmaf(tv, Wr[(H + j) * H + k], ar);
                az = fmaf(tv, Wz[(H + j) * H + k], az);
            }
            tag_r[t * H + k] = ar;
            tag_z[t * H + k] = az;
        }
    }
}

// ---- Leaf (MFMA, 512 thr / 8 waves): waves 0-3 z-cols, waves 4-7 u-cols.
__global__ __launch_bounds__(512, 1) void leaf_mfma_k(
    const int* __restrict__ word_ids, const int* __restrict__ tag_ids,
    const float* __restrict__ word_table, const ushort* __restrict__ WLzuT,
    const float* __restrict__ bu, const float* __restrict__ tag_z,
    float* __restrict__ out)
{
    __shared__ ushort Abf[16 * 328];
    __shared__ float zbuf[16][304];
    int tid = threadIdx.x;
    int node0 = blockIdx.x * 16;

    for (int idx = tid; idx < 16 * 82; idx += 512) {
        int j = idx / 82, q = idx - j * 82;
        char* rowb = (char*)(Abf + j * 328);
        if (q < 75) {
            float4 v = ((const float4*)(word_table + (long)word_ids[node0 + j] * H))[q];
            *(uint2*)(rowb + q * 8) = pack4(v);
        } else {
            *(uint2*)(rowb + q * 8) = make_uint2(0u, 0u);
        }
    }
    __syncthreads();

    int wv = tid >> 6, lane = tid & 63;
    int jrow = (lane >> 4) * 4;

    f32x4 acc[5];
    #pragma unroll
    for (int t = 0; t < 5; ++t) acc[t] = (f32x4)(0.f);

    if (wv < 4) {
        mfma_gemm<5, 10, 10, 328>(Abf, WLzuT, wv * 5, 0, lane, acc);
        int tg[4];
        #pragma unroll
        for (int q = 0; q < 4; ++q) tg[q] = tag_ids[node0 + jrow + q];
        #pragma unroll
        for (int t = 0; t < 5; ++t) {
            int c = wv * 80 + t * 16 + (lane & 15);
            #pragma unroll
            for (int q = 0; q < 4; ++q)
                if (c < 300) zbuf[jrow + q][c] = sigmoidf_(acc[t][q] + tag_z[tg[q] * H + c]);
        }
    } else {
        mfma_gemm<5, 10, 10, 328>(Abf, WLzuT, 20 + (wv - 4) * 5, 0, lane, acc);
    }
    __syncthreads();
    if (wv >= 4) {
        #pragma unroll
        for (int t = 0; t < 5; ++t) {
            int c = (wv - 4) * 80 + t * 16 + (lane & 15);
            #pragma unroll
            for (int q = 0; q < 4; ++q) {
                if (c < 300) {
                    int jn = jrow + q;
                    float u = tanhf(acc[t][q] + bu[c]);
                    out[(long)(node0 + jn) * H + c] = (1.f - zbuf[jn][c]) * u;
                }
            }
        }
    }
}

// ---- Fused internal level (512 thr / 8 waves, 16 nodes), any m ----
__device__ __forceinline__ void fused_body(
    const int* __restrict__ tag_ids, const ushort* __restrict__ WArzT,
    const ushort* __restrict__ WuTpT, const float* __restrict__ bu,
    const float* __restrict__ tag_r, const float* __restrict__ tag_z,
    float* __restrict__ out, int off, int prevOff, int m, float* __restrict__ dup,
    int node0, int tid, ushort* Abf, float (*zbuf)[304], float (*pbuf)[64][21])
{
    for (int idx = tid; idx < 16 * 154; idx += 512) {
        int j = idx / 154, q = idx - j * 154;
        char* rowb = (char*)(Abf + j * 616);
        bool valid = (node0 + j) < m;
        if (q < 75) {
            uint2 w = make_uint2(0u, 0u);
            if (valid) {
                float4 v = ((const float4*)(out + (long)(prevOff + 2 * (node0 + j)) * H))[q];
                w = pack4(v);
            }
            *(uint2*)(rowb + q * 8) = w;
        } else if (q < 150) {
            int qq = q - 75;
            uint2 w = make_uint2(0u, 0u);
            if (valid) {
                float4 v = ((const float4*)(out + (long)(prevOff + 2 * (node0 + j) + 1) * H))[qq];
                w = pack4(v);
            }
            *(uint2*)(rowb + 608 + qq * 8) = w;
        } else {
            int pb = (q == 150) ? 600 : (1208 + (q - 151) * 8);
            *(uint2*)(rowb + pb) = make_uint2(0u, 0u);
        }
    }
    __syncthreads();

    int wv = tid >> 6, lane = tid & 63;
    int jrow = (lane >> 4) * 4;
    int tg[4];
    #pragma unroll
    for (int q = 0; q < 4; ++q) {
        int gn = node0 + jrow + q;
        tg[q] = tag_ids[off + (gn < m ? gn : 0)];
    }

    f32x4 accG[5];
    #pragma unroll
    for (int t = 0; t < 5; ++t) accG[t] = (f32x4)(0.f);
    mfma_gemm<5, 19, 19, 616>(Abf, WArzT, wv * 5, 0, lane, accG);
    __syncthreads();

    float Sr[5][4];
    if (wv < 4) {
        #pragma unroll
        for (int t = 0; t < 5; ++t) {
            int c = wv * 80 + t * 16 + (lane & 15);
            #pragma unroll
            for (int q = 0; q < 4; ++q) {
                int jn = jrow + q, gn = node0 + jn;
                if (c < 300 && gn < m) {
                    float lh = out[(long)(prevOff + 2 * gn) * H + c];
                    float rh = out[(long)(prevOff + 2 * gn + 1) * H + c];
                    float r  = sigmoidf_(accG[t][q] + tag_r[tg[q] * H + c]);
                    Sr[t][q] = lh + rh;
                    Abf[jn * 616 + c]       = f2bf(r * lh);
                    Abf[jn * 616 + 304 + c] = f2bf(r * rh);
                }
            }
        }
    } else {
        #pragma unroll
        for (int t = 0; t < 5; ++t) {
            int cz = (wv - 4) * 80 + t * 16 + (lane & 15);
            #pragma unroll
            for (int q = 0; q < 4; ++q) {
                int jn = jrow + q, gn = node0 + jn;
                if (cz < 300 && gn < m)
                    zbuf[jn][cz] = sigmoidf_(accG[t][q] + tag_z[tg[q] * H + cz]);
            }
        }
    }
    __syncthreads();

    f32x4 accU[5];
    #pragma unroll
    for (int t = 0; t < 5; ++t) accU[t] = (f32x4)(0.f);
    if (wv < 4) {
        mfma_gemm<5, 10, 19, 616>(Abf, WuTpT, wv * 5, 0, lane, accU);
    } else {
        mfma_gemm<5, 9, 19, 616>(Abf, WuTpT, (wv - 4) * 5, 10, lane, accU);
        #pragma unroll
        for (int t = 0; t < 5; ++t)
            #pragma unroll
            for (int q = 0; q < 4; ++q)
                pbuf[wv - 4][lane][t * 4 + q] = accU[t][q];
    }
    __syncthreads();
    if (wv < 4) {
        #pragma unroll
        for (int t = 0; t < 5; ++t) {
            int c = wv * 80 + t * 16 + (lane & 15);
            #pragma unroll
            for (int q = 0; q < 4; ++q) {
                int jn = jrow + q, gn = node0 + jn;
                if (c < 300 && gn < m) {
                    float a = accU[t][q] + pbuf[wv][lane][t * 4 + q];
                    float u = tanhf(a + bu[c]);
                    float z = zbuf[jn][c];
                    float h = z * Sr[t][q] + (1.f - z) * u;
                    out[(long)(off + gn) * H + c] = h;
                    if (dup && gn == 0) dup[c] = h;
                }
            }
        }
    }
}

__global__ __launch_bounds__(512, 1) void level_fused_k(
    const int* __restrict__ tag_ids, const ushort* __restrict__ WArzT,
    const ushort* __restrict__ WuTpT, const float* __restrict__ bu,
    const float* __restrict__ tag_r, const float* __restrict__ tag_z,
    float* __restrict__ out, int off, int prevOff, int m)
{
    __shared__ ushort Abf[16 * 616];
    __shared__ float zbuf[16][304];
    __shared__ float pbuf[4][64][21];
    fused_body(tag_ids, WArzT, WuTpT, bu, tag_r, tag_z, out, off, prevOff, m,
               nullptr, blockIdx.x * 16, threadIdx.x, Abf, zbuf, pbuf);
}

// ---- Tail: levels m=16,8,4,2,1 in ONE block (intra-block global-write
// visibility across __syncthreads — R8/R15-validated).
__global__ __launch_bounds__(512, 1) void tail5_k(
    const int* __restrict__ tag_ids, const ushort* __restrict__ WArzT,
    const ushort* __restrict__ WuTpT, const float* __restrict__ bu,
    const float* __restrict__ tag_r, const float* __restrict__ tag_z,
    float* __restrict__ out, float* __restrict__ finalDup)
{
    __shared__ ushort Abf[16 * 616];
    __shared__ float zbuf[16][304];
    __shared__ float pbuf[4][64][21];
    int off = 8160, prevOff = 8128;
    for (int m = 16; m >= 1; m >>= 1) {
        fused_body(tag_ids, WArzT, WuTpT, bu, tag_r, tag_z, out, off, prevOff, m,
                   (m == 1) ? finalDup : nullptr, 0, threadIdx.x, Abf, zbuf, pbuf);
        __syncthreads();
        prevOff = off;
        off += m;
    }
}

extern "C" void kernel_launch(void* const* d_in, const int* in_sizes, int n_in,
                              void* d_out, int out_size, void* d_ws, size_t ws_size,
                              hipStream_t stream)
{
    const int*   word_ids   = (const int*)  d_in[0];
    const int*   tag_ids    = (const int*)  d_in[1];
    const float* word_table = (const float*)d_in[2];
    const float* tag_table  = (const float*)d_in[3];
    const float* Wr         = (const float*)d_in[4];
    const float* br         = (const float*)d_in[5];
    const float* Wz         = (const float*)d_in[6];
    const float* bz         = (const float*)d_in[7];
    const float* Wu         = (const float*)d_in[8];
    const float* bu         = (const float*)d_in[9];
    float* out = (float*)d_out;

    float* tag_r = (float*)d_ws;                  // 18000 f32
    float* tag_z = tag_r + 18000;                 // 18000 f32
    ushort* WArzT = (ushort*)(tag_z + 18000);     // 40*19*512 bf16
    ushort* WuTpT = WArzT + 40L * 19 * 512;       // 20*19*512
    ushort* WLzuT = WuTpT + 20L * 19 * 512;       // 40*10*512

    prep_k<<<700, 256, 0, stream>>>(Wr, Wz, Wu, tag_table, br, bz,
                                    WArzT, WuTpT, WLzuT, tag_r, tag_z);

    leaf_mfma_k<<<NLEAF / 16, 512, 0, stream>>>(
        word_ids, tag_ids, word_table, WLzuT, bu, tag_z, out);

    // Levels m=2048..32: one fused launch each
    int off = NLEAF, prevOff = 0;
    for (int m = 2048; m >= 32; m >>= 1) {
        level_fused_k<<<m / 16, 512, 0, stream>>>(
            tag_ids, WArzT, WuTpT, bu, tag_r, tag_z, out, off, prevOff, m);
        prevOff = off;
        off += m;
    }

    // Levels m=16..1: one single-block launch
    float* finalDup = out + (long)8191 * H;
    tail5_k<<<1, 512, 0, stream>>>(
        tag_ids, WArzT, WuTpT, bu, tag_r, tag_z, out, finalDup);
}